// Round 5
// baseline (198.027 us; speedup 1.0000x reference)
//
#include <hip/hip_runtime.h>
#include <hip/hip_bf16.h>
#include <math.h>

// DCNv1 fused, bf16-MFMA, round 5:
//  - 512-thread blocks (8 waves = 2/SIMD): waves 0-3 stage weights while
//    waves 4-7 bilinear-sample -> the two load streams overlap across SIMDs.
//  - serial 2-barrier chunk loop kept (known correct from round 4).
//  - prep_w v2: block-per-oc, LDS transpose, uint4 stores (was ~60 us).
//
// GEMM view: out[oc][pos] = sum_k w[oc][k] * col[k][pos]
//   M = OC = 256, N = B*Ho*Wo = 16384, K = C*9 = 2304, kdim = tap*256 + c
// Block: tile M=256 x N=64 (one wo row), grid 256, XCD-swizzled.
// Per wave per 32-K chunk: 4x2 MFMA tiles (16x16x32 bf16), fp32 acc.

constexpr int B  = 4;
constexpr int C  = 256;
constexpr int H  = 64;
constexpr int W  = 64;
constexpr int OC = 256;
constexpr int Ho = 64;
constexpr int Wo = 64;

constexpr int NT     = 64;   // positions per block (full row)
constexpr int CHUNKS = 72;   // 2304 / 32
constexpr int WROW   = 40;   // padded row (bf16): 80 B rows, breaks pow2 banks

typedef __attribute__((ext_vector_type(8))) short bf16x8;
typedef __attribute__((ext_vector_type(4))) float f32x4;

// ---- weight pre-pass v2: block per oc; coalesced read, uint4 writes -------
// wA[ch][oc][kk]: ch = tap*8 + chb, kk = c&31 (kk>=32 is zero pad).
__global__ __launch_bounds__(256)
void prep_w(const float* __restrict__ wt, ushort* __restrict__ wA)
{
    __shared__ ushort s[CHUNKS * WROW];       // 5760 B, [ch][40]
    const int oc = blockIdx.x;
    const int c  = threadIdx.x;               // 0..255
    const int chb = c >> 5, kk = c & 31;
    const float* wp = wt + ((size_t)oc * C + c) * 9;   // 36 B contiguous/lane
    #pragma unroll
    for (int tap = 0; tap < 9; ++tap) {
        __hip_bfloat16 hb = __float2bfloat16(wp[tap]);
        s[(tap * 8 + chb) * WROW + kk] = *(ushort*)&hb;
    }
    if (c < CHUNKS) {                          // zero the 8-entry row pads
        #pragma unroll
        for (int j = 0; j < 8; ++j) s[c * WROW + 32 + j] = 0;
    }
    __syncthreads();
    // store 72 rows x 80 B = 360 uint4, fully 16-B aligned
    const uint4* sv = (const uint4*)s;
    for (int i = c; i < CHUNKS * 5; i += 256) {
        const int row = i / 5, q = i % 5;
        ((uint4*)(wA + ((size_t)row * OC + oc) * WROW))[q] = sv[i];
    }
}

// ---------------- main fused kernel ----------------------------------------
__global__ __launch_bounds__(512, 1)
void dcn_mfma(const float* __restrict__ x, const float* __restrict__ off,
              const ushort* __restrict__ wA_g, float* __restrict__ out)
{
    __shared__ __align__(16) ushort s_wA[OC * WROW];   // 20480 B
    __shared__ __align__(16) ushort s_col[NT * WROW];  //  5120 B
    __shared__ int2   s_midx[9 * NT];                  //  4608 B
    __shared__ float4 s_mw[9 * NT];                    //  9216 B

    // XCD swizzle: blocks on one XCD share batch b and a ho-half ->
    // x[b]-half (~2.1 MB) + weights (1.47 MB) resident in 4 MB per-XCD L2.
    const int xcd = blockIdx.x & 7;
    const int ii  = blockIdx.x >> 3;            // 0..31
    const int b   = xcd & 3;
    const int ho  = ((xcd >> 2) << 5) + ii;     // half*32 + ii
    const int tid = threadIdx.x;                // 0..511

    // ---- Phase A: bilinear meta per (tap, n); zero-fold padding into wts ----
    for (int s = tid; s < 9 * NT; s += 512) {
        const int n   = s & 63;
        const int tap = s >> 6;
        const float dy = off[((size_t)(b * 18 + 2 * tap)     * Ho + ho) * Wo + n];
        const float dx = off[((size_t)(b * 18 + 2 * tap + 1) * Ho + ho) * Wo + n];
        const float ph = (float)(ho - 1 + tap / 3) + dy;
        const float pw = (float)(n  - 1 + tap % 3) + dx;
        const float h0f = floorf(ph), w0f = floorf(pw);
        const int h0 = (int)h0f, w0 = (int)w0f;
        const float lh = ph - h0f, lw = pw - w0f;
        const int wb = min(max(w0, 0), W - 2);      // pair base stays in-plane
        const int ht = min(max(h0, 0), H - 1);
        const int hb = min(max(h0 + 1, 0), H - 1);
        const float s0 = (wb == w0) ? (1.f - lw) : ((wb == w0 + 1) ? lw : 0.f);
        const float s1 = (wb + 1 == w0 + 1) ? lw : ((wb + 1 == w0) ? (1.f - lw) : 0.f);
        const float wtp = (h0 >= 0 && h0 < H)         ? (1.f - lh) : 0.f;
        const float wbt = (h0 + 1 >= 0 && h0 + 1 < H) ? lh         : 0.f;
        s_midx[s] = make_int2(ht * W + wb, hb * W + wb);
        s_mw[s]   = make_float4(wtp * s0, wtp * s1, wbt * s0, wbt * s1);
    }

    const int lane = tid & 63;
    const int wv   = tid >> 6;        // 0..7
    const int ocb  = wv >> 1;         // oc block of 64
    const int phh  = wv & 1;          // pos half of 32
    const int kq   = lane >> 4;
    const int mr   = lane & 15;

    // staging roles: waves 0-3 (tid<256) weights; waves 4-7 sampling
    const int wt_tid = tid;           // 0..255 valid when tid < 256
    const int sm_tid = tid - 256;     // 0..255 valid when tid >= 256
    const int sn  = sm_tid & 63;      // sampling position
    const int sgg = sm_tid >> 6;      // channel octet 0..3

    f32x4 acc[4][2];
    #pragma unroll
    for (int mt = 0; mt < 4; ++mt)
        #pragma unroll
        for (int nt = 0; nt < 2; ++nt)
            acc[mt][nt] = (f32x4){0.f, 0.f, 0.f, 0.f};

    for (int ch = 0; ch < CHUNKS; ++ch) {
        __syncthreads();   // prior chunk's MFMA reads done before overwrite

        if (tid < 256) {
            // ---- stage weight chunk: 80 B/thread, copy-through ----
            const uint4* src = (const uint4*)(wA_g + (size_t)ch * OC * WROW) + wt_tid * 5;
            uint4* dst = (uint4*)s_wA + wt_tid * 5;
            #pragma unroll
            for (int i = 0; i < 5; ++i) dst[i] = src[i];
        } else {
            // ---- sample 64 pos x 32 ch -> s_col (8 channels/thread) ----
            const int tap = ch >> 3;
            const int c0  = (ch & 7) << 5;
            const int2   mi = s_midx[tap * NT + sn];
            const float4 mw = s_mw[tap * NT + sn];
            union { ushort pk[8]; uint4 v; } u;
            #pragma unroll
            for (int i = 0; i < 8; ++i) {
                const float* xp = x + ((size_t)(b * C + c0 + sgg * 8 + i) << 12);
                const float v = mw.x * xp[mi.x] + mw.y * xp[mi.x + 1]
                              + mw.z * xp[mi.y] + mw.w * xp[mi.y + 1];
                __hip_bfloat16 hb = __float2bfloat16(v);
                u.pk[i] = *(ushort*)&hb;
            }
            *(uint4*)&s_col[sn * WROW + sgg * 8] = u.v;
        }
        __syncthreads();

        // ---- MFMA: 4 M-tiles x 2 N-tiles per wave ----
        bf16x8 bfr[2];
        #pragma unroll
        for (int nt = 0; nt < 2; ++nt)
            bfr[nt] = *(const bf16x8*)&s_col[((phh * 2 + nt) * 16 + mr) * WROW + kq * 8];
        #pragma unroll
        for (int mt = 0; mt < 4; ++mt) {
            const bf16x8 afr = *(const bf16x8*)&s_wA[(ocb * 64 + mt * 16 + mr) * WROW + kq * 8];
            #pragma unroll
            for (int nt = 0; nt < 2; ++nt)
                acc[mt][nt] = __builtin_amdgcn_mfma_f32_16x16x32_bf16(afr, bfr[nt], acc[mt][nt], 0, 0, 0);
        }
    }

    // ---- epilogue: C/D layout col = lane&15 (pos), row = kq*4 + r (oc) ----
    #pragma unroll
    for (int mt = 0; mt < 4; ++mt)
        #pragma unroll
        for (int nt = 0; nt < 2; ++nt)
            #pragma unroll
            for (int r = 0; r < 4; ++r) {
                const int oc = ocb * 64 + mt * 16 + kq * 4 + r;
                const int wo = (phh * 2 + nt) * 16 + mr;
                out[((size_t)(b * OC + oc) * Ho + ho) * Wo + wo] = acc[mt][nt][r];
            }
}

extern "C" void kernel_launch(void* const* d_in, const int* in_sizes, int n_in,
                              void* d_out, int out_size, void* d_ws, size_t ws_size,
                              hipStream_t stream)
{
    const float* x   = (const float*)d_in[0];
    const float* off = (const float*)d_in[1];
    const float* wt  = (const float*)d_in[2];
    float* out = (float*)d_out;
    ushort* wA = (ushort*)d_ws;   // 72*256*40*2 = 1.47 MB

    prep_w<<<OC, 256, 0, stream>>>(wt, wA);                  // 256 blocks
    dcn_mfma<<<B * Ho, 512, 0, stream>>>(x, off, wA, out);   // 256 blocks
}

// Round 6
// 196.973 us; speedup vs baseline: 1.0053x; 1.0053x over previous
//
#include <hip/hip_runtime.h>
#include <hip/hip_bf16.h>
#include <math.h>

// DCNv1 fused, bf16-MFMA, round 6: round-5 structure, sampling loads BATCHED
// (32 independent corner loads in flight per thread, then compute) — attacks
// the serialized L2 round-trips that round-5 counters exposed (VGPR=48).
//
// GEMM view: out[oc][pos] = sum_k w[oc][k] * col[k][pos]
//   M = OC = 256, N = B*Ho*Wo = 16384, K = C*9 = 2304, kdim = tap*256 + c
// Block: 512 thr (8 waves), tile M=256 x N=64 (one wo row), grid 256,
// XCD-swizzled. Waves 0-3 stage weights, waves 4-7 sample.
// Per wave per 32-K chunk: 4x2 MFMA tiles (16x16x32 bf16), fp32 acc.

constexpr int B  = 4;
constexpr int C  = 256;
constexpr int H  = 64;
constexpr int W  = 64;
constexpr int OC = 256;
constexpr int Ho = 64;
constexpr int Wo = 64;

constexpr int NT     = 64;   // positions per block (full row)
constexpr int CHUNKS = 72;   // 2304 / 32
constexpr int WROW   = 40;   // padded row (bf16): 80 B rows, breaks pow2 banks

typedef __attribute__((ext_vector_type(8))) short bf16x8;
typedef __attribute__((ext_vector_type(4))) float f32x4;

// ---- weight pre-pass: block per oc; coalesced read, uint4 writes ----------
// wA[ch][oc][kk]: ch = tap*8 + chb, kk = c&31 (kk>=32 is zero pad).
__global__ __launch_bounds__(256)
void prep_w(const float* __restrict__ wt, ushort* __restrict__ wA)
{
    __shared__ ushort s[CHUNKS * WROW];       // 5760 B, [ch][40]
    const int oc = blockIdx.x;
    const int c  = threadIdx.x;               // 0..255
    const int chb = c >> 5, kk = c & 31;
    const float* wp = wt + ((size_t)oc * C + c) * 9;   // 36 B contiguous/lane
    #pragma unroll
    for (int tap = 0; tap < 9; ++tap) {
        __hip_bfloat16 hb = __float2bfloat16(wp[tap]);
        s[(tap * 8 + chb) * WROW + kk] = *(ushort*)&hb;
    }
    if (c < CHUNKS) {                          // zero the 8-entry row pads
        #pragma unroll
        for (int j = 0; j < 8; ++j) s[c * WROW + 32 + j] = 0;
    }
    __syncthreads();
    // store 72 rows x 80 B = 360 uint4, fully 16-B aligned
    const uint4* sv = (const uint4*)s;
    for (int i = c; i < CHUNKS * 5; i += 256) {
        const int row = i / 5, q = i % 5;
        ((uint4*)(wA + ((size_t)row * OC + oc) * WROW))[q] = sv[i];
    }
}

// ---------------- main fused kernel ----------------------------------------
__global__ __launch_bounds__(512, 1)
void dcn_mfma(const float* __restrict__ x, const float* __restrict__ off,
              const ushort* __restrict__ wA_g, float* __restrict__ out)
{
    __shared__ __align__(16) ushort s_wA[OC * WROW];   // 20480 B
    __shared__ __align__(16) ushort s_col[NT * WROW];  //  5120 B
    __shared__ int2   s_midx[9 * NT];                  //  4608 B
    __shared__ float4 s_mw[9 * NT];                    //  9216 B

    // XCD swizzle: blocks on one XCD share batch b and a ho-half ->
    // x[b]-half (~2.1 MB) + weights (1.47 MB) resident in 4 MB per-XCD L2.
    const int xcd = blockIdx.x & 7;
    const int ii  = blockIdx.x >> 3;            // 0..31
    const int b   = xcd & 3;
    const int ho  = ((xcd >> 2) << 5) + ii;     // half*32 + ii
    const int tid = threadIdx.x;                // 0..511

    // ---- Phase A: bilinear meta per (tap, n); zero-fold padding into wts ----
    for (int s = tid; s < 9 * NT; s += 512) {
        const int n   = s & 63;
        const int tap = s >> 6;
        const float dy = off[((size_t)(b * 18 + 2 * tap)     * Ho + ho) * Wo + n];
        const float dx = off[((size_t)(b * 18 + 2 * tap + 1) * Ho + ho) * Wo + n];
        const float ph = (float)(ho - 1 + tap / 3) + dy;
        const float pw = (float)(n  - 1 + tap % 3) + dx;
        const float h0f = floorf(ph), w0f = floorf(pw);
        const int h0 = (int)h0f, w0 = (int)w0f;
        const float lh = ph - h0f, lw = pw - w0f;
        const int wb = min(max(w0, 0), W - 2);      // pair base stays in-plane
        const int ht = min(max(h0, 0), H - 1);
        const int hb = min(max(h0 + 1, 0), H - 1);
        const float s0 = (wb == w0) ? (1.f - lw) : ((wb == w0 + 1) ? lw : 0.f);
        const float s1 = (wb + 1 == w0 + 1) ? lw : ((wb + 1 == w0) ? (1.f - lw) : 0.f);
        const float wtp = (h0 >= 0 && h0 < H)         ? (1.f - lh) : 0.f;
        const float wbt = (h0 + 1 >= 0 && h0 + 1 < H) ? lh         : 0.f;
        s_midx[s] = make_int2(ht * W + wb, hb * W + wb);
        s_mw[s]   = make_float4(wtp * s0, wtp * s1, wbt * s0, wbt * s1);
    }

    const int lane = tid & 63;
    const int wv   = tid >> 6;        // 0..7
    const int ocb  = wv >> 1;         // oc block of 64
    const int phh  = wv & 1;          // pos half of 32
    const int kq   = lane >> 4;
    const int mr   = lane & 15;

    // staging roles: waves 0-3 (tid<256) weights; waves 4-7 sampling
    const int sm_tid = tid - 256;     // 0..255 valid when tid >= 256
    const int sn  = sm_tid & 63;      // sampling position
    const int sgg = sm_tid >> 6;      // channel octet 0..3

    f32x4 acc[4][2];
    #pragma unroll
    for (int mt = 0; mt < 4; ++mt)
        #pragma unroll
        for (int nt = 0; nt < 2; ++nt)
            acc[mt][nt] = (f32x4){0.f, 0.f, 0.f, 0.f};

    for (int ch = 0; ch < CHUNKS; ++ch) {
        __syncthreads();   // prior chunk's MFMA reads done before overwrite

        if (tid < 256) {
            // ---- stage weight chunk: 80 B/thread, batched load then store ----
            const uint4* src = (const uint4*)(wA_g + (size_t)ch * OC * WROW) + tid * 5;
            uint4 t[5];
            #pragma unroll
            for (int i = 0; i < 5; ++i) t[i] = src[i];
            uint4* dst = (uint4*)s_wA + tid * 5;
            #pragma unroll
            for (int i = 0; i < 5; ++i) dst[i] = t[i];
        } else {
            // ---- sample 64 pos x 32 ch: ALL 32 corner loads in flight ----
            const int tap = ch >> 3;
            const int c0  = (ch & 7) << 5;
            const int2   mi = s_midx[tap * NT + sn];
            const float4 mw = s_mw[tap * NT + sn];
            const float* xb = x + ((size_t)(b * C + c0 + sgg * 8) << 12);
            float t0[8], t1[8], b0[8], b1[8];
            #pragma unroll
            for (int i = 0; i < 8; ++i) {
                const float* xp = xb + ((size_t)i << 12);
                t0[i] = xp[mi.x];
                t1[i] = xp[mi.x + 1];
                b0[i] = xp[mi.y];
                b1[i] = xp[mi.y + 1];
            }
            union { ushort pk[8]; uint4 v; } u;
            #pragma unroll
            for (int i = 0; i < 8; ++i) {
                const float v = mw.x * t0[i] + mw.y * t1[i]
                              + mw.z * b0[i] + mw.w * b1[i];
                __hip_bfloat16 hb = __float2bfloat16(v);
                u.pk[i] = *(ushort*)&hb;
            }
            *(uint4*)&s_col[sn * WROW + sgg * 8] = u.v;
        }
        __syncthreads();

        // ---- MFMA: 4 M-tiles x 2 N-tiles per wave ----
        bf16x8 bfr[2];
        #pragma unroll
        for (int nt = 0; nt < 2; ++nt)
            bfr[nt] = *(const bf16x8*)&s_col[((phh * 2 + nt) * 16 + mr) * WROW + kq * 8];
        #pragma unroll
        for (int mt = 0; mt < 4; ++mt) {
            const bf16x8 afr = *(const bf16x8*)&s_wA[(ocb * 64 + mt * 16 + mr) * WROW + kq * 8];
            #pragma unroll
            for (int nt = 0; nt < 2; ++nt)
                acc[mt][nt] = __builtin_amdgcn_mfma_f32_16x16x32_bf16(afr, bfr[nt], acc[mt][nt], 0, 0, 0);
        }
    }

    // ---- epilogue: C/D layout col = lane&15 (pos), row = kq*4 + r (oc) ----
    #pragma unroll
    for (int mt = 0; mt < 4; ++mt)
        #pragma unroll
        for (int nt = 0; nt < 2; ++nt)
            #pragma unroll
            for (int r = 0; r < 4; ++r) {
                const int oc = ocb * 64 + mt * 16 + kq * 4 + r;
                const int wo = (phh * 2 + nt) * 16 + mr;
                out[((size_t)(b * OC + oc) * Ho + ho) * Wo + wo] = acc[mt][nt][r];
            }
}

extern "C" void kernel_launch(void* const* d_in, const int* in_sizes, int n_in,
                              void* d_out, int out_size, void* d_ws, size_t ws_size,
                              hipStream_t stream)
{
    const float* x   = (const float*)d_in[0];
    const float* off = (const float*)d_in[1];
    const float* wt  = (const float*)d_in[2];
    float* out = (float*)d_out;
    ushort* wA = (ushort*)d_ws;   // 72*256*40*2 = 1.47 MB

    prep_w<<<OC, 256, 0, stream>>>(wt, wA);                  // 256 blocks
    dcn_mfma<<<B * Ho, 512, 0, stream>>>(x, off, wA, out);   // 256 blocks
}

// Round 8
// 164.172 us; speedup vs baseline: 1.2062x; 1.1998x over previous
//
#include <hip/hip_runtime.h>
#include <hip/hip_bf16.h>
#include <math.h>

// DCNv1 fused, bf16-MFMA, round 8: round-7 with the prep_x store-stride bug
// fixed (dst[whw*4 + wh*2 + i]; was *8/*4 -> half-written, OOB stomping).
// x transposed to bf16 [b][cb8][hw][c32]: each corner gather is ONE dwordx4.
//
// GEMM view: out[oc][pos] = sum_k w[oc][k] * col[k][pos]
//   M = OC = 256, N = B*Ho*Wo = 16384, K = C*9 = 2304, kdim = tap*256 + c
// Block: 512 thr (8 waves), tile M=256 x N=64, grid 256, XCD-swizzled.
// Waves 0-3 stage weights, waves 4-7 sample. 4x2 MFMA tiles/wave/chunk.

constexpr int B  = 4;
constexpr int C  = 256;
constexpr int H  = 64;
constexpr int W  = 64;
constexpr int OC = 256;
constexpr int Ho = 64;
constexpr int Wo = 64;

constexpr int NT     = 64;   // positions per block (full row)
constexpr int CHUNKS = 72;   // 2304 / 32
constexpr int WROW   = 40;   // padded row (bf16): 80 B rows

typedef __attribute__((ext_vector_type(8))) short bf16x8;
typedef __attribute__((ext_vector_type(4))) float f32x4;

__device__ __forceinline__ float bf_lo(unsigned u) {
    union { unsigned i; float f; } c; c.i = u << 16; return c.f;
}
__device__ __forceinline__ float bf_hi(unsigned u) {
    union { unsigned i; float f; } c; c.i = u & 0xffff0000u; return c.f;
}

// ---- weight pre-pass: block per oc; coalesced read, uint4 writes ----------
// wA[ch][oc][kk]: ch = tap*8 + chb, kk = c&31 (kk>=32 is zero pad).
__global__ __launch_bounds__(256)
void prep_w(const float* __restrict__ wt, ushort* __restrict__ wA)
{
    __shared__ ushort s[CHUNKS * WROW];       // 5760 B, [ch][40]
    const int oc = blockIdx.x;
    const int c  = threadIdx.x;               // 0..255
    const int chb = c >> 5, kk = c & 31;
    const float* wp = wt + ((size_t)oc * C + c) * 9;   // 36 B contiguous/lane
    #pragma unroll
    for (int tap = 0; tap < 9; ++tap) {
        __hip_bfloat16 hb = __float2bfloat16(wp[tap]);
        s[(tap * 8 + chb) * WROW + kk] = *(ushort*)&hb;
    }
    if (c < CHUNKS) {                          // zero the 8-entry row pads
        #pragma unroll
        for (int j = 0; j < 8; ++j) s[c * WROW + 32 + j] = 0;
    }
    __syncthreads();
    const uint4* sv = (const uint4*)s;
    for (int i = c; i < CHUNKS * 5; i += 256) {
        const int row = i / 5, q = i % 5;
        ((uint4*)(wA + ((size_t)row * OC + oc) * WROW))[q] = sv[i];
    }
}

// ---- x pre-pass: fp32 NCHW -> bf16 [b][cb][hw][c32] (channel-interleaved) --
// Block = (b, cb, 128-hw tile): coalesced reads, LDS transpose, uint4 stores.
__global__ __launch_bounds__(256)
void prep_x(const float* __restrict__ x, ushort* __restrict__ xb)
{
    __shared__ ushort s[128 * WROW];          // [hw][40] rows, 16-B aligned
    const int blk = blockIdx.x;               // (b*8+cb)*32 + hwb
    const int hwb = blk & 31;
    const int cb  = (blk >> 5) & 7;
    const int b   = blk >> 8;
    const int hw0 = hwb << 7;
    const int t   = threadIdx.x;
    const int lhw = t & 127, chalf = t >> 7;
    #pragma unroll
    for (int i = 0; i < 16; ++i) {
        const int c = i * 2 + chalf;          // 0..31
        const float v = x[(((size_t)(b * 256 + cb * 32 + c)) << 12) + hw0 + lhw];
        __hip_bfloat16 hb = __float2bfloat16(v);
        s[lhw * WROW + c] = *(ushort*)&hb;
    }
    __syncthreads();
    // write 128 hw x 64 B contiguous: 4 uint4 per hw row, 2 per thread
    const int whw = t >> 1, wh = t & 1;
    const uint4 v0 = *(const uint4*)&s[whw * WROW + wh * 16];
    const uint4 v1 = *(const uint4*)&s[whw * WROW + wh * 16 + 8];
    uint4* dst = (uint4*)(xb + ((size_t)((b * 8 + cb) * 4096 + hw0) << 5));
    dst[whw * 4 + wh * 2 + 0] = v0;
    dst[whw * 4 + wh * 2 + 1] = v1;
}

// ---------------- main fused kernel ----------------------------------------
__global__ __launch_bounds__(512, 1)
void dcn_mfma(const ushort* __restrict__ xb, const float* __restrict__ off,
              const ushort* __restrict__ wA_g, float* __restrict__ out)
{
    __shared__ __align__(16) ushort s_wA[OC * WROW];   // 20480 B
    __shared__ __align__(16) ushort s_col[NT * WROW];  //  5120 B
    __shared__ int2   s_midx[9 * NT];                  //  4608 B
    __shared__ float4 s_mw[9 * NT];                    //  9216 B

    // XCD swizzle: blocks on one XCD share batch b and a ho-half.
    const int xcd = blockIdx.x & 7;
    const int ii  = blockIdx.x >> 3;            // 0..31
    const int b   = xcd & 3;
    const int ho  = ((xcd >> 2) << 5) + ii;     // half*32 + ii
    const int tid = threadIdx.x;                // 0..511

    // ---- Phase A: bilinear meta per (tap, n); zero-fold padding into wts ----
    for (int s = tid; s < 9 * NT; s += 512) {
        const int n   = s & 63;
        const int tap = s >> 6;
        const float dy = off[((size_t)(b * 18 + 2 * tap)     * Ho + ho) * Wo + n];
        const float dx = off[((size_t)(b * 18 + 2 * tap + 1) * Ho + ho) * Wo + n];
        const float ph = (float)(ho - 1 + tap / 3) + dy;
        const float pw = (float)(n  - 1 + tap % 3) + dx;
        const float h0f = floorf(ph), w0f = floorf(pw);
        const int h0 = (int)h0f, w0 = (int)w0f;
        const float lh = ph - h0f, lw = pw - w0f;
        const int wb = min(max(w0, 0), W - 2);      // pair base stays in-plane
        const int ht = min(max(h0, 0), H - 1);
        const int hb = min(max(h0 + 1, 0), H - 1);
        const float s0 = (wb == w0) ? (1.f - lw) : ((wb == w0 + 1) ? lw : 0.f);
        const float s1 = (wb + 1 == w0 + 1) ? lw : ((wb + 1 == w0) ? (1.f - lw) : 0.f);
        const float wtp = (h0 >= 0 && h0 < H)         ? (1.f - lh) : 0.f;
        const float wbt = (h0 + 1 >= 0 && h0 + 1 < H) ? lh         : 0.f;
        s_midx[s] = make_int2(ht * W + wb, hb * W + wb);   // hw indices
        s_mw[s]   = make_float4(wtp * s0, wtp * s1, wbt * s0, wbt * s1);
    }

    const int lane = tid & 63;
    const int wv   = tid >> 6;        // 0..7
    const int ocb  = wv >> 1;         // oc block of 64
    const int phh  = wv & 1;          // pos half of 32
    const int kq   = lane >> 4;
    const int mr   = lane & 15;

    // staging roles: waves 0-3 (tid<256) weights; waves 4-7 sampling
    const int sm_tid = tid - 256;     // 0..255 valid when tid >= 256
    const int sn  = sm_tid & 63;      // sampling position
    const int sgg = sm_tid >> 6;      // channel octet 0..3

    f32x4 acc[4][2];
    #pragma unroll
    for (int mt = 0; mt < 4; ++mt)
        #pragma unroll
        for (int nt = 0; nt < 2; ++nt)
            acc[mt][nt] = (f32x4){0.f, 0.f, 0.f, 0.f};

    for (int ch = 0; ch < CHUNKS; ++ch) {
        __syncthreads();   // prior chunk's MFMA reads done before overwrite

        if (tid < 256) {
            // ---- stage weight chunk: 80 B/thread ----
            const uint4* src = (const uint4*)(wA_g + (size_t)ch * OC * WROW) + tid * 5;
            uint4 t[5];
            #pragma unroll
            for (int i = 0; i < 5; ++i) t[i] = src[i];
            uint4* dst = (uint4*)s_wA + tid * 5;
            #pragma unroll
            for (int i = 0; i < 5; ++i) dst[i] = t[i];
        } else {
            // ---- sample: 4 corners x 8 bf16 channels, each ONE dwordx4 ----
            const int tap = ch >> 3;
            const int cb  = ch & 7;
            const int2   mi = s_midx[tap * NT + sn];
            const float4 mw = s_mw[tap * NT + sn];
            const ushort* xp = xb + ((size_t)(b * 8 + cb) << 17) + (sgg << 3);
            const uint4 c00 = *(const uint4*)(xp + ((size_t)mi.x << 5));
            const uint4 c01 = *(const uint4*)(xp + (((size_t)mi.x + 1) << 5));
            const uint4 c10 = *(const uint4*)(xp + ((size_t)mi.y << 5));
            const uint4 c11 = *(const uint4*)(xp + (((size_t)mi.y + 1) << 5));
            union { ushort pk[8]; uint4 v; } u;
            const unsigned a00[4] = {c00.x, c00.y, c00.z, c00.w};
            const unsigned a01[4] = {c01.x, c01.y, c01.z, c01.w};
            const unsigned a10[4] = {c10.x, c10.y, c10.z, c10.w};
            const unsigned a11[4] = {c11.x, c11.y, c11.z, c11.w};
            #pragma unroll
            for (int j = 0; j < 4; ++j) {
                const float vlo = mw.x * bf_lo(a00[j]) + mw.y * bf_lo(a01[j])
                                + mw.z * bf_lo(a10[j]) + mw.w * bf_lo(a11[j]);
                const float vhi = mw.x * bf_hi(a00[j]) + mw.y * bf_hi(a01[j])
                                + mw.z * bf_hi(a10[j]) + mw.w * bf_hi(a11[j]);
                __hip_bfloat16 l = __float2bfloat16(vlo);
                __hip_bfloat16 h = __float2bfloat16(vhi);
                u.pk[2 * j]     = *(ushort*)&l;
                u.pk[2 * j + 1] = *(ushort*)&h;
            }
            *(uint4*)&s_col[sn * WROW + sgg * 8] = u.v;
        }
        __syncthreads();

        // ---- MFMA: 4 M-tiles x 2 N-tiles per wave ----
        bf16x8 bfr[2];
        #pragma unroll
        for (int nt = 0; nt < 2; ++nt)
            bfr[nt] = *(const bf16x8*)&s_col[((phh * 2 + nt) * 16 + mr) * WROW + kq * 8];
        #pragma unroll
        for (int mt = 0; mt < 4; ++mt) {
            const bf16x8 afr = *(const bf16x8*)&s_wA[(ocb * 64 + mt * 16 + mr) * WROW + kq * 8];
            #pragma unroll
            for (int nt = 0; nt < 2; ++nt)
                acc[mt][nt] = __builtin_amdgcn_mfma_f32_16x16x32_bf16(afr, bfr[nt], acc[mt][nt], 0, 0, 0);
        }
    }

    // ---- epilogue: C/D layout col = lane&15 (pos), row = kq*4 + r (oc) ----
    #pragma unroll
    for (int mt = 0; mt < 4; ++mt)
        #pragma unroll
        for (int nt = 0; nt < 2; ++nt)
            #pragma unroll
            for (int r = 0; r < 4; ++r) {
                const int oc = ocb * 64 + mt * 16 + kq * 4 + r;
                const int wo = (phh * 2 + nt) * 16 + mr;
                out[((size_t)(b * OC + oc) * Ho + ho) * Wo + wo] = acc[mt][nt][r];
            }
}

extern "C" void kernel_launch(void* const* d_in, const int* in_sizes, int n_in,
                              void* d_out, int out_size, void* d_ws, size_t ws_size,
                              hipStream_t stream)
{
    const float* x   = (const float*)d_in[0];
    const float* off = (const float*)d_in[1];
    const float* wt  = (const float*)d_in[2];
    float* out = (float*)d_out;
    ushort* wA = (ushort*)d_ws;                   // 72*256*40*2 = 1.47 MB
    ushort* xb = wA + (size_t)CHUNKS * OC * WROW; // 4*8*4096*32*2 = 8.4 MB

    prep_w<<<OC, 256, 0, stream>>>(wt, wA);                    // 256 blocks
    prep_x<<<B * 8 * 32, 256, 0, stream>>>(x, xb);             // 1024 blocks
    dcn_mfma<<<B * Ho, 512, 0, stream>>>(xb, off, wA, out);    // 256 blocks
}

// Round 9
// 127.826 us; speedup vs baseline: 1.5492x; 1.2843x over previous
//
#include <hip/hip_runtime.h>
#include <hip/hip_bf16.h>
#include <math.h>

// DCNv1 fused, bf16-MFMA, round 9:
//  - 2-way K-split: grid 512 (2 blocks/CU), block = (b, ho, khalf) does 36
//    chunks -> partial fp32 in ws; float4 reduce kernel sums the halves.
//  - weight staging via __builtin_amdgcn_global_load_lds width=16 (identity
//    copy; wave-uniform lds base + lane*16 matches the flat layout).
//  - prep_w fused into prep_x (single prep kernel) to probe the ~55us
//    mystery cost that tracked the prep_w node across rounds 2-8.
// Fallback: if ws_size can't hold partials, ksplit=1 (round-8 shape).

constexpr int B  = 4;
constexpr int C  = 256;
constexpr int H  = 64;
constexpr int W  = 64;
constexpr int OC = 256;
constexpr int Ho = 64;
constexpr int Wo = 64;

constexpr int NT     = 64;   // positions per block (full wo row)
constexpr int CHUNKS = 72;   // 2304 / 32
constexpr int WROW   = 40;   // padded row (bf16): 80 B rows

constexpr size_t WA_ELTS  = (size_t)CHUNKS * OC * WROW;     // 737280 ushorts
constexpr size_t XB_ELTS  = (size_t)B * 8 * 4096 * 32;      // 4194304 ushorts
constexpr size_t OUT_ELTS = (size_t)B * OC * Ho * Wo;       // 4194304 floats

typedef __attribute__((ext_vector_type(8))) short bf16x8;
typedef __attribute__((ext_vector_type(4))) float f32x4;

__device__ __forceinline__ float bf_lo(unsigned u) {
    union { unsigned i; float f; } c; c.i = u << 16; return c.f;
}
__device__ __forceinline__ float bf_hi(unsigned u) {
    union { unsigned i; float f; } c; c.i = u & 0xffff0000u; return c.f;
}

// ---- fused pre-pass: blocks 0..1023 transpose x, blocks 1024..1279 do w ----
__global__ __launch_bounds__(256)
void prep_all(const float* __restrict__ x, const float* __restrict__ wt,
              ushort* __restrict__ xb, ushort* __restrict__ wA)
{
    __shared__ ushort sx[128 * WROW];         // x path: [hw][40]
    __shared__ ushort sw[CHUNKS * WROW];      // w path: [ch][40]
    const int t = threadIdx.x;

    if (blockIdx.x < 1024) {
        // ---- x: fp32 NCHW -> bf16 [b][cb][hw][c32] ----
        const int blk = blockIdx.x;           // (b*8+cb)*32 + hwb
        const int hwb = blk & 31;
        const int cb  = (blk >> 5) & 7;
        const int b   = blk >> 8;
        const int hw0 = hwb << 7;
        const int lhw = t & 127, chalf = t >> 7;
        #pragma unroll
        for (int i = 0; i < 16; ++i) {
            const int c = i * 2 + chalf;      // 0..31
            const float v = x[(((size_t)(b * 256 + cb * 32 + c)) << 12) + hw0 + lhw];
            __hip_bfloat16 hb = __float2bfloat16(v);
            sx[lhw * WROW + c] = *(ushort*)&hb;
        }
        __syncthreads();
        const int whw = t >> 1, wh = t & 1;   // 4 uint4 per 64-B hw row
        const uint4 v0 = *(const uint4*)&sx[whw * WROW + wh * 16];
        const uint4 v1 = *(const uint4*)&sx[whw * WROW + wh * 16 + 8];
        uint4* dst = (uint4*)(xb + ((size_t)((b * 8 + cb) * 4096 + hw0) << 5));
        dst[whw * 4 + wh * 2 + 0] = v0;
        dst[whw * 4 + wh * 2 + 1] = v1;
    } else {
        // ---- w: fp32 [oc][c][tap] -> bf16 wA[ch][oc][40] ----
        const int oc = blockIdx.x - 1024;
        const int c  = t;
        const int chb = c >> 5, kk = c & 31;
        const float* wp = wt + ((size_t)oc * C + c) * 9;
        #pragma unroll
        for (int tap = 0; tap < 9; ++tap) {
            __hip_bfloat16 hb = __float2bfloat16(wp[tap]);
            sw[(tap * 8 + chb) * WROW + kk] = *(ushort*)&hb;
        }
        if (c < CHUNKS) {
            #pragma unroll
            for (int j = 0; j < 8; ++j) sw[c * WROW + 32 + j] = 0;
        }
        __syncthreads();
        const uint4* sv = (const uint4*)sw;
        for (int i = c; i < CHUNKS * 5; i += 256) {
            const int row = i / 5, q = i % 5;
            ((uint4*)(wA + ((size_t)row * OC + oc) * WROW))[q] = sv[i];
        }
    }
}

// ---------------- main fused kernel ----------------------------------------
__global__ __launch_bounds__(512, 1)
void dcn_mfma(const ushort* __restrict__ xb, const float* __restrict__ off,
              const ushort* __restrict__ wA_g, float* __restrict__ out0,
              int ksplit)
{
    __shared__ __align__(16) ushort s_wA[OC * WROW];   // 20480 B
    __shared__ __align__(16) ushort s_col[NT * WROW];  //  5120 B
    __shared__ int2   s_midx[9 * NT];                  //  4608 B
    __shared__ float4 s_mw[9 * NT];                    //  9216 B

    // XCD swizzle: same b / ho-half (and both khalves) pinned per XCD.
    const int xcd = blockIdx.x & 7;
    const int ii  = blockIdx.x >> 3;
    const int b   = xcd & 3;
    int ho, khalf;
    if (ksplit == 2) { khalf = ii & 1; ho = ((xcd >> 2) << 5) + (ii >> 1); }
    else             { khalf = 0;      ho = ((xcd >> 2) << 5) + ii;        }
    const int ch0 = khalf * 36;
    const int ch1 = ch0 + (ksplit == 2 ? 36 : 72);
    float* outp = out0 + (size_t)khalf * OUT_ELTS;  // slice 0 aliases out0
    const int tid = threadIdx.x;

    // ---- Phase A: bilinear meta per (tap, n); zero-fold padding into wts ----
    for (int s = tid; s < 9 * NT; s += 512) {
        const int n   = s & 63;
        const int tap = s >> 6;
        const float dy = off[((size_t)(b * 18 + 2 * tap)     * Ho + ho) * Wo + n];
        const float dx = off[((size_t)(b * 18 + 2 * tap + 1) * Ho + ho) * Wo + n];
        const float ph = (float)(ho - 1 + tap / 3) + dy;
        const float pw = (float)(n  - 1 + tap % 3) + dx;
        const float h0f = floorf(ph), w0f = floorf(pw);
        const int h0 = (int)h0f, w0 = (int)w0f;
        const float lh = ph - h0f, lw = pw - w0f;
        const int wb = min(max(w0, 0), W - 2);
        const int ht = min(max(h0, 0), H - 1);
        const int hb = min(max(h0 + 1, 0), H - 1);
        const float s0 = (wb == w0) ? (1.f - lw) : ((wb == w0 + 1) ? lw : 0.f);
        const float s1 = (wb + 1 == w0 + 1) ? lw : ((wb + 1 == w0) ? (1.f - lw) : 0.f);
        const float wtp = (h0 >= 0 && h0 < H)         ? (1.f - lh) : 0.f;
        const float wbt = (h0 + 1 >= 0 && h0 + 1 < H) ? lh         : 0.f;
        s_midx[s] = make_int2(ht * W + wb, hb * W + wb);
        s_mw[s]   = make_float4(wtp * s0, wtp * s1, wbt * s0, wbt * s1);
    }

    const int lane = tid & 63;
    const int wv   = tid >> 6;        // 0..7
    const int ocb  = wv >> 1;         // oc block of 64
    const int phh  = wv & 1;          // pos half of 32
    const int kq   = lane >> 4;
    const int mr   = lane & 15;

    const int sm_tid = tid - 256;     // sampling threads: tid >= 256
    const int sn  = sm_tid & 63;
    const int sgg = sm_tid >> 6;

    f32x4 acc[4][2];
    #pragma unroll
    for (int mt = 0; mt < 4; ++mt)
        #pragma unroll
        for (int nt = 0; nt < 2; ++nt)
            acc[mt][nt] = (f32x4){0.f, 0.f, 0.f, 0.f};

    for (int ch = ch0; ch < ch1; ++ch) {
        __syncthreads();   // prior chunk's MFMA reads done before overwrite

        if (tid < 256) {
            // ---- weights -> LDS via direct DMA, identity-copy layout ----
            // 20 KB/chunk = 20 segs of 1 KB (64 lanes x 16 B); waves 0-3 x5.
            #pragma unroll
            for (int i = 0; i < 5; ++i) {
                const int seg = wv * 5 + i;            // wave-uniform
                __builtin_amdgcn_global_load_lds(
                    (const __attribute__((address_space(1))) void*)
                        (wA_g + (size_t)ch * OC * WROW + seg * 512 + lane * 8),
                    (__attribute__((address_space(3))) void*)&s_wA[seg * 512],
                    16, 0, 0);
            }
        } else {
            // ---- sample: 4 corners x 8 bf16 channels, each ONE dwordx4 ----
            const int tap = ch >> 3;
            const int cb  = ch & 7;
            const int2   mi = s_midx[tap * NT + sn];
            const float4 mw = s_mw[tap * NT + sn];
            const ushort* xp = xb + ((size_t)(b * 8 + cb) << 17) + (sgg << 3);
            const uint4 c00 = *(const uint4*)(xp + ((size_t)mi.x << 5));
            const uint4 c01 = *(const uint4*)(xp + (((size_t)mi.x + 1) << 5));
            const uint4 c10 = *(const uint4*)(xp + ((size_t)mi.y << 5));
            const uint4 c11 = *(const uint4*)(xp + (((size_t)mi.y + 1) << 5));
            union { ushort pk[8]; uint4 v; } u;
            const unsigned a00[4] = {c00.x, c00.y, c00.z, c00.w};
            const unsigned a01[4] = {c01.x, c01.y, c01.z, c01.w};
            const unsigned a10[4] = {c10.x, c10.y, c10.z, c10.w};
            const unsigned a11[4] = {c11.x, c11.y, c11.z, c11.w};
            #pragma unroll
            for (int j = 0; j < 4; ++j) {
                const float vlo = mw.x * bf_lo(a00[j]) + mw.y * bf_lo(a01[j])
                                + mw.z * bf_lo(a10[j]) + mw.w * bf_lo(a11[j]);
                const float vhi = mw.x * bf_hi(a00[j]) + mw.y * bf_hi(a01[j])
                                + mw.z * bf_hi(a10[j]) + mw.w * bf_hi(a11[j]);
                __hip_bfloat16 l = __float2bfloat16(vlo);
                __hip_bfloat16 h = __float2bfloat16(vhi);
                u.pk[2 * j]     = *(ushort*)&l;
                u.pk[2 * j + 1] = *(ushort*)&h;
            }
            *(uint4*)&s_col[sn * WROW + sgg * 8] = u.v;
        }
        __syncthreads();   // drains the global_load_lds DMAs too (vmcnt)

        // ---- MFMA: 4 M-tiles x 2 N-tiles per wave ----
        bf16x8 bfr[2];
        #pragma unroll
        for (int nt = 0; nt < 2; ++nt)
            bfr[nt] = *(const bf16x8*)&s_col[((phh * 2 + nt) * 16 + mr) * WROW + kq * 8];
        #pragma unroll
        for (int mt = 0; mt < 4; ++mt) {
            const bf16x8 afr = *(const bf16x8*)&s_wA[(ocb * 64 + mt * 16 + mr) * WROW + kq * 8];
            #pragma unroll
            for (int nt = 0; nt < 2; ++nt)
                acc[mt][nt] = __builtin_amdgcn_mfma_f32_16x16x32_bf16(afr, bfr[nt], acc[mt][nt], 0, 0, 0);
        }
    }

    // ---- epilogue: C/D layout col = lane&15 (pos), row = kq*4 + r (oc) ----
    #pragma unroll
    for (int mt = 0; mt < 4; ++mt)
        #pragma unroll
        for (int nt = 0; nt < 2; ++nt)
            #pragma unroll
            for (int r = 0; r < 4; ++r) {
                const int oc = ocb * 64 + mt * 16 + kq * 4 + r;
                const int wo = (phh * 2 + nt) * 16 + mr;
                outp[((size_t)(b * OC + oc) * Ho + ho) * Wo + wo] = acc[mt][nt][r];
            }
}

// ---- reduce: out = p0 + p1 (float4) ---------------------------------------
__global__ __launch_bounds__(256)
void reduce2(const float4* __restrict__ p0, const float4* __restrict__ p1,
             float4* __restrict__ out)
{
    const int i = blockIdx.x * 256 + threadIdx.x;   // over OUT_ELTS/4
    const float4 a = p0[i], b = p1[i];
    out[i] = make_float4(a.x + b.x, a.y + b.y, a.z + b.z, a.w + b.w);
}

extern "C" void kernel_launch(void* const* d_in, const int* in_sizes, int n_in,
                              void* d_out, int out_size, void* d_ws, size_t ws_size,
                              hipStream_t stream)
{
    const float* x   = (const float*)d_in[0];
    const float* off = (const float*)d_in[1];
    const float* wt  = (const float*)d_in[2];
    float* out = (float*)d_out;

    ushort* wA = (ushort*)d_ws;                 // 1.47 MB
    ushort* xb = wA + WA_ELTS;                  // 8.39 MB
    float*  po = (float*)(xb + XB_ELTS);        // partials: 2 x 16.78 MB
    const size_t need = (WA_ELTS + XB_ELTS) * sizeof(ushort)
                      + 2 * OUT_ELTS * sizeof(float);
    const int ksplit = (ws_size >= need) ? 2 : 1;

    prep_all<<<1280, 256, 0, stream>>>(x, wt, xb, wA);

    if (ksplit == 2) {
        dcn_mfma<<<512, 512, 0, stream>>>(xb, off, wA, po, 2);
        reduce2<<<(int)(OUT_ELTS / 4 / 256), 256, 0, stream>>>(
            (const float4*)po, (const float4*)(po + OUT_ELTS), (float4*)out);
    } else {
        dcn_mfma<<<256, 512, 0, stream>>>(xb, off, wA, out, 1);
    }
}